// Round 12
// baseline (567.977 us; speedup 1.0000x reference)
//
#include <hip/hip_runtime.h>
#include <hip/hip_cooperative_groups.h>
#include <hip/hip_bf16.h>

#define D 64            // D_IN == D_OUT == 64
#define K 24            // slots/node; deg~Poisson(10): P(>24)~3e-5 -> ~10 spill edges (inline, exact)
#define M44 ((1ULL << 44) - 1)
#define SPILLCAP 65536

namespace cg = cooperative_groups;

struct FParams {
    const float* x; const int* rowi; const int* coli; const float* ew;
    const float* W; const float* bias; float* out;
    unsigned long long* packed; int* spillCnt; unsigned int* slots;
    float* dis; int* cnt; int4* spill;
    int n; int nE; int ntiles;
};

// ---------------------------------------------------------------------------
// k_fused: ALL phases in one cooperative kernel -- r11 accounting showed
// ~60us (of 213) living in dispatch boundaries; grid.sync() removes them.
//  stage W -> [zero] sync [build] sync [dis] sync [gather+gemm grid-stride].
// Phase bodies are the r8/r11-proven shapes verbatim. launch_bounds(256,8)
// caps VGPR at 64 so 8 blocks/CU co-reside (LDS 20KB x 8 = 160KiB exact).
__global__ __launch_bounds__(256, 8) void k_fused(FParams p) {
    cg::grid_group grid = cg::this_grid();
    __shared__ float Bs[D * D];        // 16 KB: Bs[k][o] = W[o][k], swizzled
    __shared__ float Ast[16 * D];      // 4 KB: 16-row A tile, swizzled slots
    float4* Ast4 = (float4*)Ast;
    int tid = threadIdx.x;
    int gid = blockIdx.x * 256 + tid;
    int gsz = gridDim.x * 256;

    // stage W once (overlaps phase 1)
    const float4* W4 = (const float4*)p.W;
#pragma unroll
    for (int v = 0; v < 4; ++v) {
        int idx = tid + v * 256;
        int o  = idx >> 4;
        int kc = idx & 15;
        float4 wv = W4[idx];
        int gq = o >> 2, oo = o & 3;
        { int k = 4 * kc + 0; Bs[k * 64 + 4 * ((gq + k) & 15) + oo] = wv.x; }
        { int k = 4 * kc + 1; Bs[k * 64 + 4 * ((gq + k) & 15) + oo] = wv.y; }
        { int k = 4 * kc + 2; Bs[k * 64 + 4 * ((gq + k) & 15) + oo] = wv.z; }
        { int k = 4 * kc + 3; Bs[k * 64 + 4 * ((gq + k) & 15) + oo] = wv.w; }
    }

    // phase 1: zero packed + spillCnt
    for (int i = gid; i < p.n; i += gsz) p.packed[i] = 0ULL;
    if (gid == 0) *p.spillCnt = 0;
    grid.sync();

    // phase 2: build (r8 body; grid-stride <=2 edges/thread at G=2048)
    for (int e = gid; e < p.nE; e += gsz) {
        int r = p.rowi[e];
        int c = p.coli[e];
        float w = p.ew[e];
        unsigned long long fx = (unsigned long long)((double)w * 4294967296.0);
        unsigned long long old = atomicAdd(&p.packed[r], (1ULL << 44) | fx);
        int rank = (int)(old >> 44);
        if (rank < K) {
            int q = (int)(w * 32768.0f + 0.5f);
            if (q > 32767) q = 32767;
            p.slots[r * K + rank] = ((unsigned int)c << 15) | (unsigned int)q;
        } else {
            int pp = atomicAdd(p.spillCnt, 1);
            if (pp < SPILLCAP) p.spill[pp] = make_int4(r, c, __float_as_int(w), 0);
        }
    }
    grid.sync();

    // phase 3: dis/cnt
    for (int i = gid; i < p.n; i += gsz) {
        unsigned long long pk = p.packed[i];
        float dg = (float)(1.0 + (double)(pk & M44) * (1.0 / 4294967296.0));
        p.dis[i] = rsqrtf(dg);
        p.cnt[i] = (int)(pk >> 44);
    }
    grid.sync();

    // phase 4: gather+gemm, grid-stride over 16-row tiles (TLP = full machine)
    int j   = tid & 15;
    int grp = tid >> 4;
    const float4* x4 = (const float4*)p.x;
    float4 bv = ((const float4*)p.bias)[j];
    for (int tile = blockIdx.x; tile < p.ntiles; tile += gridDim.x) {
        int i0 = tile * 16;
        int i  = i0 + grp;
        float4 acc = make_float4(0.f, 0.f, 0.f, 0.f);
        if (i < p.n) {
            int rawc = p.cnt[i];
            int c_n = rawc < K ? rawc : K;
            int s = i * K;
            for (int off = 0; off < c_n; off += 16) {
                int idx = off + j;
                unsigned int rec = 0u;
                float wj = 0.f;
                if (idx < c_n) {
                    rec = p.slots[s + idx];
                    wj = (float)(rec & 32767u) * (1.0f / 32768.0f) * p.dis[rec >> 15];
                }
                int mm = c_n - off; if (mm > 16) mm = 16;
#pragma unroll
                for (int t = 0; t < 16; ++t) {
                    if (t < mm) {
                        int col = (int)((unsigned int)__shfl((int)rec, t, 16) >> 15);
                        float w = __shfl(wj, t, 16);
                        float4 xv = x4[col * 16 + j];
                        acc.x += w * xv.x; acc.y += w * xv.y;
                        acc.z += w * xv.z; acc.w += w * xv.w;
                    }
                }
            }
            if (rawc > K) {
                int total = *p.spillCnt;
                if (total > SPILLCAP) total = SPILLCAP;
                for (int sp = 0; sp < total; ++sp) {
                    int4 v = p.spill[sp];
                    if (v.x == i) {
                        float w = __int_as_float(v.z) * p.dis[v.y];
                        float4 xv = x4[v.y * 16 + j];
                        acc.x += w * xv.x; acc.y += w * xv.y;
                        acc.z += w * xv.z; acc.w += w * xv.w;
                    }
                }
            }
            float di = p.dis[i];
            float4 xi = x4[i * 16 + j];
            acc.x = di * (di * xi.x + acc.x);
            acc.y = di * (di * xi.y + acc.y);
            acc.z = di * (di * xi.z + acc.z);
            acc.w = di * (di * xi.w + acc.w);
        }
        Ast4[grp * 16 + ((j + (grp >> 2)) & 15)] = acc;
        __syncthreads();

        float4 oacc = bv;
#pragma unroll 4
        for (int kc = 0; kc < 16; ++kc) {
            float4 a4 = Ast4[grp * 16 + ((kc + (grp >> 2)) & 15)];
            float4 b0 = *(const float4*)&Bs[(4 * kc + 0) * 64 + 4 * ((j + 4 * kc + 0) & 15)];
            float4 b1 = *(const float4*)&Bs[(4 * kc + 1) * 64 + 4 * ((j + 4 * kc + 1) & 15)];
            float4 b2 = *(const float4*)&Bs[(4 * kc + 2) * 64 + 4 * ((j + 4 * kc + 2) & 15)];
            float4 b3 = *(const float4*)&Bs[(4 * kc + 3) * 64 + 4 * ((j + 4 * kc + 3) & 15)];
            oacc.x += a4.x * b0.x + a4.y * b1.x + a4.z * b2.x + a4.w * b3.x;
            oacc.y += a4.x * b0.y + a4.y * b1.y + a4.z * b2.y + a4.w * b3.y;
            oacc.z += a4.x * b0.z + a4.y * b1.z + a4.z * b2.z + a4.w * b3.z;
            oacc.w += a4.x * b0.w + a4.y * b1.w + a4.z * b2.w + a4.w * b3.w;
        }
        int r = i0 + grp;
        if (r < p.n) ((float4*)p.out)[r * 16 + j] = oacc;
        __syncthreads();   // protect Ast before next tile's gather writes
    }
}

// ---------------------------------------------------------------------------
// FALLBACK: r11 kernels verbatim (used if cooperative launch unavailable).
__global__ __launch_bounds__(256) void k_build(const int* __restrict__ rowi,
                                               const int* __restrict__ coli,
                                               const float* __restrict__ ew,
                                               unsigned long long* __restrict__ packed,
                                               unsigned int* __restrict__ slots,
                                               int4* __restrict__ spill,
                                               int* __restrict__ spillCnt, int nE) {
    int e = blockIdx.x * 256 + threadIdx.x;
    if (e >= nE) return;
    int r = rowi[e];
    int c = coli[e];
    float w = ew[e];
    unsigned long long fx = (unsigned long long)((double)w * 4294967296.0);
    unsigned long long old = atomicAdd(&packed[r], (1ULL << 44) | fx);
    int rank = (int)(old >> 44);
    if (rank < K) {
        int q = (int)(w * 32768.0f + 0.5f);
        if (q > 32767) q = 32767;
        slots[r * K + rank] = ((unsigned int)c << 15) | (unsigned int)q;
    } else {
        int p = atomicAdd(spillCnt, 1);
        if (p < SPILLCAP) spill[p] = make_int4(r, c, __float_as_int(w), 0);
    }
}

__global__ __launch_bounds__(256) void k_dis(const unsigned long long* __restrict__ packed,
                                             float* __restrict__ dis,
                                             int* __restrict__ cnt, int n) {
    int i = blockIdx.x * 256 + threadIdx.x;
    if (i >= n) return;
    unsigned long long p = packed[i];
    float dg = (float)(1.0 + (double)(p & M44) * (1.0 / 4294967296.0));
    dis[i] = rsqrtf(dg);
    cnt[i] = (int)(p >> 44);
}

__global__ __launch_bounds__(256) void k_gather_gemm(const float* __restrict__ x,
                                                     const float* __restrict__ dis,
                                                     const int* __restrict__ cnt,
                                                     const unsigned int* __restrict__ slots,
                                                     const int4* __restrict__ spill,
                                                     const int* __restrict__ spillCnt,
                                                     const float* __restrict__ W,
                                                     const float* __restrict__ bias,
                                                     float* __restrict__ out, int n) {
    __shared__ float Bs[D * D];
    __shared__ float Ast[16 * D];
    float4* Ast4 = (float4*)Ast;
    int tid = threadIdx.x;

    const float4* W4 = (const float4*)W;
#pragma unroll
    for (int v = 0; v < 4; ++v) {
        int idx = tid + v * 256;
        int o  = idx >> 4;
        int kc = idx & 15;
        float4 wv = W4[idx];
        int gq = o >> 2, oo = o & 3;
        { int k = 4 * kc + 0; Bs[k * 64 + 4 * ((gq + k) & 15) + oo] = wv.x; }
        { int k = 4 * kc + 1; Bs[k * 64 + 4 * ((gq + k) & 15) + oo] = wv.y; }
        { int k = 4 * kc + 2; Bs[k * 64 + 4 * ((gq + k) & 15) + oo] = wv.z; }
        { int k = 4 * kc + 3; Bs[k * 64 + 4 * ((gq + k) & 15) + oo] = wv.w; }
    }

    int j   = tid & 15;
    int grp = tid >> 4;
    int i0  = blockIdx.x * 16;
    int i   = i0 + grp;

    float4 acc = make_float4(0.f, 0.f, 0.f, 0.f);
    const float4* x4 = (const float4*)x;
    if (i < n) {
        int rawc = cnt[i];
        int c_n = rawc < K ? rawc : K;
        int s = i * K;
        for (int off = 0; off < c_n; off += 16) {
            int idx = off + j;
            unsigned int rec = 0u;
            float wj = 0.f;
            if (idx < c_n) {
                rec = slots[s + idx];
                wj = (float)(rec & 32767u) * (1.0f / 32768.0f) * dis[rec >> 15];
            }
            int mm = c_n - off; if (mm > 16) mm = 16;
#pragma unroll
            for (int t = 0; t < 16; ++t) {
                if (t < mm) {
                    int col = (int)((unsigned int)__shfl((int)rec, t, 16) >> 15);
                    float w = __shfl(wj, t, 16);
                    float4 xv = x4[col * 16 + j];
                    acc.x += w * xv.x; acc.y += w * xv.y;
                    acc.z += w * xv.z; acc.w += w * xv.w;
                }
            }
        }
        if (rawc > K) {
            int total = *spillCnt;
            if (total > SPILLCAP) total = SPILLCAP;
            for (int sp = 0; sp < total; ++sp) {
                int4 v = spill[sp];
                if (v.x == i) {
                    float w = __int_as_float(v.z) * dis[v.y];
                    float4 xv = x4[v.y * 16 + j];
                    acc.x += w * xv.x; acc.y += w * xv.y;
                    acc.z += w * xv.z; acc.w += w * xv.w;
                }
            }
        }
        float di = dis[i];
        float4 xi = x4[i * 16 + j];
        acc.x = di * (di * xi.x + acc.x);
        acc.y = di * (di * xi.y + acc.y);
        acc.z = di * (di * xi.z + acc.z);
        acc.w = di * (di * xi.w + acc.w);
    }
    Ast4[grp * 16 + ((j + (grp >> 2)) & 15)] = acc;
    __syncthreads();

    float4 oacc = ((const float4*)bias)[j];
#pragma unroll 4
    for (int kc = 0; kc < 16; ++kc) {
        float4 a4 = Ast4[grp * 16 + ((kc + (grp >> 2)) & 15)];
        float4 b0 = *(const float4*)&Bs[(4 * kc + 0) * 64 + 4 * ((j + 4 * kc + 0) & 15)];
        float4 b1 = *(const float4*)&Bs[(4 * kc + 1) * 64 + 4 * ((j + 4 * kc + 1) & 15)];
        float4 b2 = *(const float4*)&Bs[(4 * kc + 2) * 64 + 4 * ((j + 4 * kc + 2) & 15)];
        float4 b3 = *(const float4*)&Bs[(4 * kc + 3) * 64 + 4 * ((j + 4 * kc + 3) & 15)];
        oacc.x += a4.x * b0.x + a4.y * b1.x + a4.z * b2.x + a4.w * b3.x;
        oacc.y += a4.x * b0.y + a4.y * b1.y + a4.z * b2.y + a4.w * b3.y;
        oacc.z += a4.x * b0.z + a4.y * b1.z + a4.z * b2.z + a4.w * b3.z;
        oacc.w += a4.x * b0.w + a4.y * b1.w + a4.z * b2.w + a4.w * b3.w;
    }
    int r = i0 + grp;
    if (r < n) ((float4*)out)[r * 16 + j] = oacc;
}

extern "C" void kernel_launch(void* const* d_in, const int* in_sizes, int n_in,
                              void* d_out, int out_size, void* d_ws, size_t ws_size,
                              hipStream_t stream) {
    const float* x    = (const float*)d_in[0];
    const int*   ei   = (const int*)d_in[1];   // [2*E] flat: rows then cols
    const float* ew   = (const float*)d_in[2];
    const float* W    = (const float*)d_in[3];
    const float* bias = (const float*)d_in[4];
    float* out = (float*)d_out;

    int n  = in_sizes[0] / D;   // 100000
    int nE = in_sizes[2];       // 1000000
    const int* rowi = ei;
    const int* coli = ei + nE;

    // workspace (~12.2 MB): packed | spillCnt | slots | dis | cnt | spill
    char* w = (char*)d_ws;
    unsigned long long* packed = (unsigned long long*)w; w += (size_t)n * 8;
    int* spillCnt = (int*)w;                             w += 64;
    unsigned int* slots = (unsigned int*)w;              w += (size_t)n * K * 4;
    float* dis = (float*)w;                              w += (size_t)n * 4;
    int*   cnt = (int*)w;                                w += (size_t)n * 4;
    int4*  spill = (int4*)w;

    int ntiles = (n + 15) / 16;

    // cooperative path: single dispatch, grid sized to co-residency
    bool coop_done = false;
    int occ = 0;
    hipError_t oerr = hipOccupancyMaxActiveBlocksPerMultiprocessor(&occ, k_fused, 256, 0);
    if (oerr == hipSuccess && occ > 0) {
        int G = occ * 256;                 // 256 CUs on MI355X (gfx950)
        if (G > 2048) G = 2048;
        FParams p;
        p.x = x; p.rowi = rowi; p.coli = coli; p.ew = ew; p.W = W; p.bias = bias;
        p.out = out; p.packed = packed; p.spillCnt = spillCnt; p.slots = slots;
        p.dis = dis; p.cnt = cnt; p.spill = spill;
        p.n = n; p.nE = nE; p.ntiles = ntiles;
        void* args[] = { (void*)&p };
        hipError_t lerr = hipLaunchCooperativeKernel(k_fused, dim3(G), dim3(256),
                                                     args, 0, stream);
        coop_done = (lerr == hipSuccess);
    }

    if (!coop_done) {
        // r11 fallback (213us proven)
        int gn = (n + 255) / 256;
        int gE = (nE + 255) / 256;
        hipMemsetAsync(packed, 0, (size_t)n * 8 + 64, stream);
        k_build<<<gE, 256, 0, stream>>>(rowi, coli, ew, packed, slots, spill, spillCnt, nE);
        k_dis  <<<gn, 256, 0, stream>>>(packed, dis, cnt, n);
        k_gather_gemm<<<ntiles, 256, 0, stream>>>(x, dis, cnt, slots, spill, spillCnt, W, bias, out, n);
    }
}

// Round 13
// 210.631 us; speedup vs baseline: 2.6965x; 2.6965x over previous
//
#include <hip/hip_runtime.h>
#include <hip/hip_bf16.h>

#define D 64            // D_IN == D_OUT == 64
#define K 24            // slots/node; deg~Poisson(10): P(>24)~3e-5 -> ~10 spill edges (inline, exact)
#define M44 ((1ULL << 44) - 1)
#define SPILLCAP 65536

// ---------------------------------------------------------------------------
// k_build: SINGLE-PASS CSR (r8/r11-proven 76us shape — 1 edge/thread, max TLP).
// One packed 64-bit atomic/edge (count->rank high 20 bits, fixed-point ew sum
// low 44 -> exact deg) + one direct 4B record store slots[row*K+rank].
// Record: (col<<15)|q15(ew).
// MEASURED WALLS: ~21.5G RMW/s device atomics (r5/r6: sharding flat ->
// throughput-bound); r10: 2 edges/thread regresses (89us) — keep 1/thread;
// r12: cooperative fusion regresses (TLP loss) — keep separate dispatches.
__global__ __launch_bounds__(256) void k_build(const int* __restrict__ rowi,
                                               const int* __restrict__ coli,
                                               const float* __restrict__ ew,
                                               unsigned long long* __restrict__ packed,
                                               unsigned int* __restrict__ slots,
                                               int4* __restrict__ spill,
                                               int* __restrict__ spillCnt, int nE) {
    int e = blockIdx.x * 256 + threadIdx.x;
    if (e >= nE) return;
    int r = rowi[e];
    int c = coli[e];
    float w = ew[e];
    unsigned long long fx = (unsigned long long)((double)w * 4294967296.0);
    unsigned long long old = atomicAdd(&packed[r], (1ULL << 44) | fx);
    int rank = (int)(old >> 44);
    if (rank < K) {
        int q = (int)(w * 32768.0f + 0.5f);
        if (q > 32767) q = 32767;
        slots[r * K + rank] = ((unsigned int)c << 15) | (unsigned int)q;
    } else {
        int p = atomicAdd(spillCnt, 1);
        if (p < SPILLCAP) spill[p] = make_int4(r, c, __float_as_int(w), 0);
    }
}

// lazy dis: rsqrt(1 + sum_ew) straight from the packed word (float path:
// 44-bit fixed -> float loses ~2^-24 rel on deg -> ~1e-7 on dis; invisible
// at 0.1 tolerance).  Replaces the whole k_dis dispatch (r13).
__device__ __forceinline__ float dis_of(unsigned long long pk) {
    return rsqrtf(1.0f + (float)(pk & M44) * (1.0f / 4294967296.0f));
}

// k_gather_gemm: r11-PROVEN FUSION (6250 blocks, 1 node per 16-lane group —
// FULL TLP; r7/r12 both prove shrinking this grid loses).  W staged first
// (overlaps gather latency).  Neighbor dis computed lazily from packed[col]
// (8B, L2-resident 800KB) in the prefetch lane.  Rare overflow nodes
// (rawc>K) scan the tiny spill list inline.  One barrier (covers Bs + Ast),
// then the 16x64 mini-GEMM at LDS bank floor.
__global__ __launch_bounds__(256) void k_gather_gemm(const float* __restrict__ x,
                                                     const unsigned long long* __restrict__ packed,
                                                     const unsigned int* __restrict__ slots,
                                                     const int4* __restrict__ spill,
                                                     const int* __restrict__ spillCnt,
                                                     const float* __restrict__ W,
                                                     const float* __restrict__ bias,
                                                     float* __restrict__ out, int n) {
    __shared__ float Bs[D * D];        // 16 KB: Bs[k][o] = W[o][k], swizzled
    __shared__ float Ast[16 * D];      // 4 KB: 16-row A tile, swizzled slots
    float4* Ast4 = (float4*)Ast;
    int tid = threadIdx.x;

    // Phase 0: stage W (issue first; overlaps the gather's global loads)
    const float4* W4 = (const float4*)W;
#pragma unroll
    for (int v = 0; v < 4; ++v) {
        int idx = tid + v * 256;       // 0..1023
        int o  = idx >> 4;             // out-ch 0..63
        int kc = idx & 15;
        float4 wv = W4[idx];
        int gq = o >> 2, oo = o & 3;
        { int k = 4 * kc + 0; Bs[k * 64 + 4 * ((gq + k) & 15) + oo] = wv.x; }
        { int k = 4 * kc + 1; Bs[k * 64 + 4 * ((gq + k) & 15) + oo] = wv.y; }
        { int k = 4 * kc + 2; Bs[k * 64 + 4 * ((gq + k) & 15) + oo] = wv.z; }
        { int k = 4 * kc + 3; Bs[k * 64 + 4 * ((gq + k) & 15) + oo] = wv.w; }
    }

    // Phase 1: gather (one node per 16-lane group)
    int j   = tid & 15;                // k-chunk lane
    int grp = tid >> 4;                // 0..15
    int i0  = blockIdx.x * 16;
    int i   = i0 + grp;

    float4 acc = make_float4(0.f, 0.f, 0.f, 0.f);
    const float4* x4 = (const float4*)x;
    if (i < n) {
        unsigned long long pk = packed[i];
        int rawc = (int)(pk >> 44);
        int c_n = rawc < K ? rawc : K;
        int s = i * K;
        for (int off = 0; off < c_n; off += 16) {
            int idx = off + j;
            unsigned int rec = 0u;
            float wj = 0.f;
            if (idx < c_n) {
                rec = slots[s + idx];
                wj = (float)(rec & 32767u) * (1.0f / 32768.0f) * dis_of(packed[rec >> 15]);
            }
            int mm = c_n - off; if (mm > 16) mm = 16;
#pragma unroll
            for (int t = 0; t < 16; ++t) {
                if (t < mm) {
                    int col = (int)((unsigned int)__shfl((int)rec, t, 16) >> 15);
                    float w = __shfl(wj, t, 16);
                    float4 xv = x4[col * 16 + j];
                    acc.x += w * xv.x; acc.y += w * xv.y;
                    acc.z += w * xv.z; acc.w += w * xv.w;
                }
            }
        }
        if (rawc > K) {                // statistically ~10 edges in the graph
            int total = *spillCnt;
            if (total > SPILLCAP) total = SPILLCAP;
            for (int sp = 0; sp < total; ++sp) {
                int4 v = spill[sp];    // broadcast (same addr all lanes)
                if (v.x == i) {
                    float w = __int_as_float(v.z) * dis_of(packed[v.y]);
                    float4 xv = x4[v.y * 16 + j];
                    acc.x += w * xv.x; acc.y += w * xv.y;
                    acc.z += w * xv.z; acc.w += w * xv.w;
                }
            }
        }
        float di = dis_of(pk);
        float4 xi = x4[i * 16 + j];
        acc.x = di * (di * xi.x + acc.x);
        acc.y = di * (di * xi.y + acc.y);
        acc.z = di * (di * xi.z + acc.z);
        acc.w = di * (di * xi.w + acc.w);
    }
    Ast4[grp * 16 + ((j + (grp >> 2)) & 15)] = acc;   // swizzled slot
    __syncthreads();                   // covers Bs staging + Ast tile

    // Phase 2: 16x64 mini-GEMM (thread: row=grp', out-chs 4j..4j+3)
    int row = tid >> 4;
    int cg  = tid & 15;
    float4 oacc = ((const float4*)bias)[cg];
#pragma unroll 4
    for (int kc = 0; kc < 16; ++kc) {
        float4 a4 = Ast4[row * 16 + ((kc + (row >> 2)) & 15)];
        float4 b0 = *(const float4*)&Bs[(4 * kc + 0) * 64 + 4 * ((cg + 4 * kc + 0) & 15)];
        float4 b1 = *(const float4*)&Bs[(4 * kc + 1) * 64 + 4 * ((cg + 4 * kc + 1) & 15)];
        float4 b2 = *(const float4*)&Bs[(4 * kc + 2) * 64 + 4 * ((cg + 4 * kc + 2) & 15)];
        float4 b3 = *(const float4*)&Bs[(4 * kc + 3) * 64 + 4 * ((cg + 4 * kc + 3) & 15)];
        oacc.x += a4.x * b0.x + a4.y * b1.x + a4.z * b2.x + a4.w * b3.x;
        oacc.y += a4.x * b0.y + a4.y * b1.y + a4.z * b2.y + a4.w * b3.y;
        oacc.z += a4.x * b0.z + a4.y * b1.z + a4.z * b2.z + a4.w * b3.z;
        oacc.w += a4.x * b0.w + a4.y * b1.w + a4.z * b2.w + a4.w * b3.w;
    }
    int r = i0 + row;
    if (r < n) ((float4*)out)[r * 16 + cg] = oacc;
}

extern "C" void kernel_launch(void* const* d_in, const int* in_sizes, int n_in,
                              void* d_out, int out_size, void* d_ws, size_t ws_size,
                              hipStream_t stream) {
    const float* x    = (const float*)d_in[0];
    const int*   ei   = (const int*)d_in[1];   // [2*E] flat: rows then cols
    const float* ew   = (const float*)d_in[2];
    const float* W    = (const float*)d_in[3];
    const float* bias = (const float*)d_in[4];
    float* out = (float*)d_out;

    int n  = in_sizes[0] / D;   // 100000
    int nE = in_sizes[2];       // 1000000
    const int* rowi = ei;
    const int* coli = ei + nE;

    // workspace (~11.4 MB): packed | spillCnt | slots | spill
    char* w = (char*)d_ws;
    unsigned long long* packed = (unsigned long long*)w; w += (size_t)n * 8;
    int* spillCnt = (int*)w;                             w += 64;
    unsigned int* slots = (unsigned int*)w;              w += (size_t)n * K * 4;
    int4* spill = (int4*)w;

    int gE = (nE + 255) / 256;
    int gT = (n + 15) / 16;     // 6250 blocks: 16 nodes/block, 1 node/group

    hipMemsetAsync(packed, 0, (size_t)n * 8 + 64, stream);   // packed + spillCnt
    k_build<<<gE, 256, 0, stream>>>(rowi, coli, ew, packed, slots, spill, spillCnt, nE);
    k_gather_gemm<<<gT, 256, 0, stream>>>(x, packed, slots, spill, spillCnt, W, bias, out, n);
}